// Round 3
// baseline (72.610 us; speedup 1.0000x reference)
//
#include <hip/hip_runtime.h>
#include <math.h>

// S4D kernel materialization:
//   out[d,l] = dt_d * sum_n Re{ (Cr + i Ci) * B * exp(dt_d * (Ar + i Ai) * l) }
// D=1024, N=64, L=1024, fp32.
//
// R3 design:
//  - One block per d, BLOCK=512 = 64 t-lanes x 8 n-splits (8 n per thread)
//    -> 8 waves/SIMD (vs R2's 4) for latency hiding.
//  - l = t + 64*j, j<16 (CHUNK=16): setup cost amortized over 2x outputs.
//  - No transcendentals in main loop: state(t) = hiT[n][t>>4] * loT[n][t&15]
//    from LDS tables (broadcast / conflict-free reads).
//  - 3-term real recurrence u_{j+1} = 2Re(r) u_j - |r|^2 u_{j-1},
//    r = exp(dtA*64); {2Re(r), -|r|^2} precomputed in LDS (saves 3 VALU/n).
//  - LDS union: build tables (11.5 KB) first, reuse storage for the 7-way
//    n-split reduction buffer (28 KB) after the main loop.

#define D_MODEL 1024
#define N_STATE 64
#define SEQ_LEN 1024
#define CHUNK   16
#define TPD     64                  // t-lanes per d; l = t + 64*j
#define NSPLIT  8
#define NPT     (N_STATE / NSPLIT)  // 8 n per thread
#define BLOCK   (TPD * NSPLIT)      // 512

#define INV_2PI 0.15915494309189535

__device__ __forceinline__ float sin_rev(float f) { return __builtin_amdgcn_sinf(f); }
__device__ __forceinline__ float cos_rev(float f) { return __builtin_amdgcn_cosf(f); }

union SMem {
  struct {
    float2 hiT[N_STATE][4];    // exp(dtA*16k), k<4        2 KB
    float2 loT[N_STATE][16];   // exp(dtA*m),   m<16       8 KB
    float4 wsA[N_STATE];       // {wr, wi, str, sti}       1 KB
    float2 wsB[N_STATE];       // {2*Re(r), -|r|^2}        0.5 KB
  } tab;
  float red[NSPLIT - 1][TPD][CHUNK];  // reduction         28 KB
};

__global__ __launch_bounds__(BLOCK, 8) void s4d_kernel(
    const float* __restrict__ A_real, const float* __restrict__ A_imag,
    const float* __restrict__ C, const float* __restrict__ log_dt,
    const float* __restrict__ B, float* __restrict__ out)
{
  __shared__ SMem sm;

  const int tid = threadIdx.x;
  const int d   = blockIdx.x;
  const float dt = __expf(log_dt[d]);

  // ---- build tables: 64 n x 20 entries = 1280, <=3 per thread ----
  #pragma unroll
  for (int i = 0; i < 3; ++i) {
    const int e = tid + BLOCK * i;
    if (e < N_STATE * 20) {
      const int n   = e / 20;
      const int idx = e - n * 20;
      const int steps = (idx < 4) ? (idx << 4) : (idx - 4);
      const float ar = A_real[d * N_STATE + n];
      const float ai = A_imag[d * N_STATE + n];
      const float xr = dt * ar;
      const double drev = (double)dt * (double)ai * INV_2PI;  // rev / unit l
      const double ph = drev * (double)steps;
      const float  fr = (float)(ph - floor(ph));
      const float mag = __expf(xr * (float)steps);
      const float2 v = make_float2(mag * cos_rev(fr), mag * sin_rev(fr));
      if (idx < 4) sm.tab.hiT[n][idx] = v; else sm.tab.loT[n][idx - 4] = v;
    }
  }
  if (tid < N_STATE) {
    const int n = tid;
    const float ar = A_real[d * N_STATE + n];
    const float ai = A_imag[d * N_STATE + n];
    const float b  = B[d * N_STATE + n];
    const float cr = C[(d * N_STATE + n) * 2 + 0];
    const float ci = C[(d * N_STATE + n) * 2 + 1];
    const float xr = dt * ar;
    const double drev = (double)dt * (double)ai * INV_2PI;
    const double ph = drev * (double)TPD;              // r = exp(dtA*64)
    const float  fr = (float)(ph - floor(ph));
    const float mag = __expf(xr * (float)TPD);
    const float str = mag * cos_rev(fr);
    const float sti = mag * sin_rev(fr);
    sm.tab.wsA[n] = make_float4(cr * b * dt, ci * b * dt, str, sti);
    sm.tab.wsB[n] = make_float2(str + str, -(mag * mag));
  }
  __syncthreads();

  const int t     = tid & (TPD - 1);
  const int split = tid >> 6;          // == wave id
  const int thi   = t >> 4;
  const int tlo   = t & 15;

  float acc[CHUNK];
  #pragma unroll
  for (int j = 0; j < CHUNK; ++j) acc[j] = 0.0f;

  const int n0 = split * NPT;
  #pragma unroll 2
  for (int nn = 0; nn < NPT; ++nn) {
    const int n = n0 + nn;
    const float4 w4 = sm.tab.wsA[n];
    const float2 ab = sm.tab.wsB[n];
    const float2 h  = sm.tab.hiT[n][thi];
    const float2 l2 = sm.tab.loT[n][tlo];
    // state(t) = h * l2
    const float sr = fmaf(h.x, l2.x, -(h.y * l2.y));
    const float si = fmaf(h.x, l2.y,   h.y * l2.x);
    // y0 = w * state; seeds u0 = Re(y0), u1 = Re(y0 * r)
    float u0 = fmaf(w4.x, sr, -(w4.y * si));
    const float yi = fmaf(w4.x, si, w4.y * sr);
    float u1 = fmaf(u0, w4.z, -(yi * w4.w));
    acc[0] += u0;
    acc[1] += u1;
    #pragma unroll
    for (int j = 2; j < CHUNK; ++j) {
      const float u2 = fmaf(ab.x, u1, ab.y * u0);
      acc[j] += u2;
      u0 = u1; u1 = u2;
    }
  }

  // ---- 8-way n-split reduction (reuses table LDS) + store ----
  __syncthreads();   // all table reads done before red overwrite
  if (split != 0) {
    float4* r4 = (float4*)sm.red[split - 1][t];
    #pragma unroll
    for (int q = 0; q < 4; ++q)
      r4[q] = make_float4(acc[4*q], acc[4*q+1], acc[4*q+2], acc[4*q+3]);
  }
  __syncthreads();
  if (split == 0) {
    #pragma unroll
    for (int s = 0; s < NSPLIT - 1; ++s) {
      const float4* r4 = (const float4*)sm.red[s][t];
      #pragma unroll
      for (int q = 0; q < 4; ++q) {
        const float4 v = r4[q];
        acc[4*q]   += v.x; acc[4*q+1] += v.y;
        acc[4*q+2] += v.z; acc[4*q+3] += v.w;
      }
    }
    float* op = out + d * SEQ_LEN + t;
    #pragma unroll
    for (int j = 0; j < CHUNK; ++j) op[j * TPD] = acc[j];
  }
}

extern "C" void kernel_launch(void* const* d_in, const int* in_sizes, int n_in,
                              void* d_out, int out_size, void* d_ws, size_t ws_size,
                              hipStream_t stream) {
  const float* A_real = (const float*)d_in[0];
  const float* A_imag = (const float*)d_in[1];
  const float* C      = (const float*)d_in[2];
  const float* log_dt = (const float*)d_in[3];
  const float* B      = (const float*)d_in[4];
  float* out = (float*)d_out;

  s4d_kernel<<<dim3(D_MODEL), dim3(BLOCK), 0, stream>>>(
      A_real, A_imag, C, log_dt, B, out);
}